// Round 5
// baseline (134.039 us; speedup 1.0000x reference)
//
#include <hip/hip_runtime.h>

typedef float v2f __attribute__((ext_vector_type(2)));

#define BATCH   4
#define NPTS    4096      // 64*64 top-surface points per batch
#define MPTS    8192      // cloud points per batch
#define TPB     256
#define VPT     16        // points per thread (register tile); must be >=12 to stay VALU-bound
#define DEPTH   256       // opposite-side points staged per block
#define MSPLIT  (MPTS / DEPTH)            // 32 chunks over M (dist1)
#define NSPLIT  (NPTS / DEPTH)            // 16 chunks over N (dist2)
#define D1_BLOCKS (BATCH * MSPLIT)        // 128 (each covers all 4096 n)
#define D2_BLOCKS (BATCH * 2 * NSPLIT)    // 128 (2 m-halves of 8192)
#define NBLOCKS  (D1_BLOCKS + D2_BLOCKS)  // 256
#define BIGF    1.0e30f
#define POISON  0xAAAAAAAAu               // harness 0xAA poison; > any non-negative float bits

// ws float layout: dist1f[BATCH*NPTS], dist2f[BATCH*MPTS], ctrl[16]
// ctrl[8..11] = nvalid per batch (float atomicAdd; poison base -3e-13 is negligible)
// ctrl[12]    = ticket (uint; base = POISON, deterministic per launch)

// vertices [B,3,64,32,64]; take y=31 (last), n = x*64 + z
__device__ __forceinline__ float vtop(const float* __restrict__ v, int b, int c, int n) {
    return v[b * 393216 + c * 131072 + ((n >> 6) << 11) + 1984 + (n & 63)];
}

__device__ __forceinline__ float aload(float* p) {
    return __hip_atomic_load(p, __ATOMIC_RELAXED, __HIP_MEMORY_SCOPE_AGENT);
}

// min over DEPTH staged points; 2 VALU inst/pair via v_pk_fma_f32 + v_min3_f32
__device__ __forceinline__ void chunk_min(const float* __restrict__ sx,
                                          const float* __restrict__ sy,
                                          const float* __restrict__ sz,
                                          const float* __restrict__ sw,
                                          const v2f* __restrict__ ax,
                                          const v2f* __restrict__ ay,
                                          const v2f* __restrict__ az,
                                          float* __restrict__ best) {
#pragma unroll 2
    for (int j = 0; j < DEPTH; j += 4) {
        const float4 x4 = *(const float4*)&sx[j];   // broadcast reads, conflict-free
        const float4 y4 = *(const float4*)&sy[j];
        const float4 z4 = *(const float4*)&sz[j];
        const float4 w4 = *(const float4*)&sw[j];
        const v2f xa = {x4.x, x4.y}, xb = {x4.z, x4.w};
        const v2f ya = {y4.x, y4.y}, yb = {y4.z, y4.w};
        const v2f za = {z4.x, z4.y}, zb = {z4.z, z4.w};
        const v2f wa = {w4.x, w4.y}, wb = {w4.z, w4.w};
#pragma unroll
        for (int k = 0; k < VPT; ++k) {
            const v2f e0 = __builtin_elementwise_fma(ax[k], xa,
                           __builtin_elementwise_fma(ay[k], ya,
                           __builtin_elementwise_fma(az[k], za, wa)));
            const v2f e1 = __builtin_elementwise_fma(ax[k], xb,
                           __builtin_elementwise_fma(ay[k], yb,
                           __builtin_elementwise_fma(az[k], zb, wb)));
            best[k] = fminf(fminf(best[k], e0.x), e0.y);   // v_min3_f32
            best[k] = fminf(fminf(best[k], e1.x), e1.y);
        }
    }
}

__global__ void __launch_bounds__(TPB, 1) fused_kernel(const float* __restrict__ vert,
                                                       const float* __restrict__ pc,
                                                       float* __restrict__ dist1f,
                                                       float* __restrict__ dist2f,
                                                       float* __restrict__ ctrl,
                                                       float* __restrict__ out) {
    __shared__ __align__(16) float sx[DEPTH], sy[DEPTH], sz[DEPTH], sw[DEPTH];
    __shared__ unsigned s_old;
    __shared__ float rs[4];
    const int tid = threadIdx.x;
    const int blk = blockIdx.x;

    v2f ax[VPT], ay[VPT], az[VPT];
    float best[VPT];

    if (blk < D1_BLOCKS) {
        // ---- dist1: thread owns 16 v-points; min over a 256-point q chunk ----
        const int c = blk % MSPLIT;
        const int b = blk / MSPLIT;
        const float* pcb = pc + (size_t)b * 3 * MPTS;

        {   // stage q chunk: (qx,qy,qz, 0.5||q||^2 or BIG if padded)
            const int m = c * DEPTH + tid;
            const float qx = pcb[m], qy = pcb[MPTS + m], qz = pcb[2 * MPTS + m];
            const bool valid = !(qx == 0.0f && qy == 0.0f && qz == 0.0f);
            sx[tid] = qx; sy[tid] = qy; sz[tid] = qz;
            sw[tid] = valid ? 0.5f * (qx * qx + qy * qy + qz * qz) : BIGF;
        }
#pragma unroll
        for (int k = 0; k < VPT; ++k) {
            const int n = k * TPB + tid;
            const float x = (vtop(vert, b, 0, n) - 0.5f) * 2.0f;
            const float y = (vtop(vert, b, 1, n) - 0.5f) * 2.0f;
            const float z = (vtop(vert, b, 2, n) - 0.5f) * 2.0f;
            ax[k] = (v2f){-x, -x}; ay[k] = (v2f){-y, -y}; az[k] = (v2f){-z, -z};
            best[k] = BIGF;
        }
        __syncthreads();

        chunk_min(sx, sy, sz, sw, ax, ay, az, best);

        float* d1b = dist1f + b * NPTS;
#pragma unroll
        for (int k = 0; k < VPT; ++k) {
            const int n = k * TPB + tid;
            const float vv = ax[k].x * ax[k].x + ay[k].x * ay[k].x + az[k].x * az[k].x;
            const float d = fmaxf(fmaf(2.0f, best[k], vv), 0.0f);
            atomicMin((unsigned*)&d1b[n], __float_as_uint(d));  // poison 0xAA.. acts as +inf
        }
    } else {
        // ---- dist2: thread owns 16 p-points (one m-half); min over a 256-point v chunk ----
        const int blk2 = blk - D1_BLOCKS;
        const int c    = blk2 % NSPLIT;
        const int half = (blk2 / NSPLIT) & 1;
        const int b    = blk2 / (NSPLIT * 2);
        const float* pcb = pc + (size_t)b * 3 * MPTS;

        {   // stage v chunk
            const int n = c * DEPTH + tid;
            const float x = (vtop(vert, b, 0, n) - 0.5f) * 2.0f;
            const float y = (vtop(vert, b, 1, n) - 0.5f) * 2.0f;
            const float z = (vtop(vert, b, 2, n) - 0.5f) * 2.0f;
            sx[tid] = x; sy[tid] = y; sz[tid] = z;
            sw[tid] = 0.5f * (x * x + y * y + z * z);
        }
        const int mbase = half * (TPB * VPT) + tid;
        unsigned vmask = 0u;
#pragma unroll
        for (int k = 0; k < VPT; ++k) {
            const int m = mbase + k * TPB;
            const float qx = pcb[m], qy = pcb[MPTS + m], qz = pcb[2 * MPTS + m];
            if (!(qx == 0.0f && qy == 0.0f && qz == 0.0f)) vmask |= (1u << k);
            ax[k] = (v2f){-qx, -qx}; ay[k] = (v2f){-qy, -qy}; az[k] = (v2f){-qz, -qz};
            best[k] = BIGF;
        }
        __syncthreads();

        chunk_min(sx, sy, sz, sw, ax, ay, az, best);

        float* d2b = dist2f + b * MPTS;
#pragma unroll
        for (int k = 0; k < VPT; ++k) {
            const int m = mbase + k * TPB;
            const float qq = ax[k].x * ax[k].x + ay[k].x * ay[k].x + az[k].x * az[k].x;
            float d = fmaxf(fmaf(2.0f, best[k], qq), 0.0f);
            if (!((vmask >> k) & 1u)) d = 0.0f;   // invalid -> forces final value to 0
            atomicMin((unsigned*)&d2b[m], __float_as_uint(d));
        }
        if (c == 0) {   // count valid points once per (b, half)
            float cnt = (float)__popc(vmask);
            for (int off = 32; off > 0; off >>= 1) cnt += __shfl_down(cnt, off, 64);
            if ((tid & 63) == 0) atomicAdd(&ctrl[8 + b], cnt);
        }
    }

    // ---- arrival ticket; last block finalizes ----
    __threadfence();
    __syncthreads();
    if (tid == 0) s_old = atomicAdd((unsigned*)&ctrl[12], 1u);
    __syncthreads();
    if (s_old == POISON + (unsigned)(NBLOCKS - 1)) {
        float acc = 0.0f;
#pragma unroll
        for (int bb = 0; bb < BATCH; ++bb) {
            const float nv = fmaxf(aload(&ctrl[8 + bb]), 1.0f);
            const float w1 = 1.0f / (float)(NPTS * BATCH);
            const float w2 = 1.0f / (nv * BATCH);
            float* p1 = dist1f + bb * NPTS;
            for (int i = tid; i < NPTS; i += TPB) acc += aload(&p1[i]) * w1;
            float* p2 = dist2f + bb * MPTS;
            for (int i = tid; i < MPTS; i += TPB) acc += aload(&p2[i]) * w2;
        }
        for (int off = 32; off > 0; off >>= 1) acc += __shfl_down(acc, off, 64);
        if ((tid & 63) == 0) rs[tid >> 6] = acc;
        __syncthreads();
        if (tid == 0) out[0] = rs[0] + rs[1] + rs[2] + rs[3];
    }
}

extern "C" void kernel_launch(void* const* d_in, const int* in_sizes, int n_in,
                              void* d_out, int out_size, void* d_ws, size_t ws_size,
                              hipStream_t stream) {
    const float* vert = (const float*)d_in[0];
    const float* pc   = (const float*)d_in[1];
    float* out = (float*)d_out;

    float* dist1f = (float*)d_ws;                 // BATCH*NPTS
    float* dist2f = dist1f + BATCH * NPTS;        // BATCH*MPTS
    float* ctrl   = dist2f + BATCH * MPTS;        // 16 floats

    fused_kernel<<<NBLOCKS, TPB, 0, stream>>>(vert, pc, dist1f, dist2f, ctrl, out);
}

// Round 6
// 86.698 us; speedup vs baseline: 1.5461x; 1.5461x over previous
//
#include <hip/hip_runtime.h>

#define BATCH   4
#define NPTS    4096      // 64*64 top-surface points per batch
#define MPTS    8192      // cloud points per batch
#define TPB     256
#define VPT     8         // points per thread (register tile)
#define MSPLIT  32        // dist1: chunks over M -> MLEN=256
#define NSPLIT  16        // dist2: chunks over N -> NLEN=256
#define MLEN    (MPTS / MSPLIT)           // 256
#define NLEN    (NPTS / NSPLIT)           // 256
#define D1_NBLK (NPTS / (TPB * VPT))      // 2
#define D2_MBLK (MPTS / (TPB * VPT))      // 4
#define D1_BLOCKS (BATCH * D1_NBLK * MSPLIT)  // 256
#define D2_BLOCKS (BATCH * D2_MBLK * NSPLIT)  // 256
#define BIGF    1.0e30f

#define PART1_ELEMS (MSPLIT * BATCH * NPTS)   // 524288 floats (2 MB)
#define PART2_ELEMS (NSPLIT * BATCH * MPTS)   // 524288 floats (2 MB)

// reduce: 4 points per thread via float4
#define R1_BLOCKS ((BATCH * NPTS) / (TPB * 4))   // 16
#define R2_BLOCKS ((BATCH * MPTS) / (TPB * 4))   // 32
#define R_BLOCKS  (R1_BLOCKS + R2_BLOCKS)        // 48

// ctrl layout (floats): [0..3]=sum dist1 per batch, [4..7]=sum valid dist2,
// [8..11]=nvalid, [15]=ticket (as uint bits)
#define CTRL_FLOATS 16

// vertices [B,3,64,32,64]; take y=31 (last), n = x*64 + z
__device__ __forceinline__ float vtop(const float* __restrict__ v, int b, int c, int n) {
    return v[b * 393216 + c * 131072 + ((n >> 6) << 11) + 1984 + (n & 63)];
}

__global__ void __launch_bounds__(TPB) dist_kernel(const float* __restrict__ vert,
                                                   const float* __restrict__ pc,
                                                   float* __restrict__ part1,
                                                   float* __restrict__ part2,
                                                   float* __restrict__ ctrl) {
    __shared__ float4 tile[TPB];
    const int tid = threadIdx.x;
    int blk = blockIdx.x;

    if (blk == 0 && tid < CTRL_FLOATS) ctrl[tid] = 0.0f;   // zeroes sums + ticket

    if (blk < D1_BLOCKS) {
        // ---- dist1: each thread owns 8 v-points; min over a 256-point q chunk ----
        const int c  = blk % MSPLIT;
        const int nb = (blk / MSPLIT) % D1_NBLK;
        const int b  = blk / (MSPLIT * D1_NBLK);
        const float* pcb = pc + (size_t)b * 3 * MPTS;

        {   // stage q chunk: (qx,qy,qz, 0.5*||q||^2 or BIG if padded)
            const int m = c * MLEN + tid;
            const float qx = pcb[m], qy = pcb[MPTS + m], qz = pcb[2 * MPTS + m];
            const bool valid = !(qx == 0.0f && qy == 0.0f && qz == 0.0f);
            const float qn2 = valid ? 0.5f * (qx * qx + qy * qy + qz * qz) : BIGF;
            tile[tid] = make_float4(qx, qy, qz, qn2);
        }

        float vx[VPT], vy[VPT], vz[VPT], best[VPT];
        const int nbase = nb * (TPB * VPT) + tid;
#pragma unroll
        for (int k = 0; k < VPT; ++k) {
            const int n = nbase + k * TPB;
            vx[k] = (vtop(vert, b, 0, n) - 0.5f) * 2.0f;
            vy[k] = (vtop(vert, b, 1, n) - 0.5f) * 2.0f;
            vz[k] = (vtop(vert, b, 2, n) - 0.5f) * 2.0f;
            best[k] = BIGF;
        }
        __syncthreads();

#pragma unroll 4
        for (int j = 0; j < MLEN; ++j) {
            const float4 q = tile[j];
#pragma unroll
            for (int k = 0; k < VPT; ++k) {
                // e = 0.5||q||^2 - v.q   (3 fma with neg modifiers + 1 min)
                best[k] = fminf(best[k],
                    fmaf(-vx[k], q.x, fmaf(-vy[k], q.y, fmaf(-vz[k], q.z, q.w))));
            }
        }

        float* outp = part1 + (size_t)c * (BATCH * NPTS) + (size_t)b * NPTS;
#pragma unroll
        for (int k = 0; k < VPT; ++k) {
            const int n = nbase + k * TPB;
            const float vv = vx[k]*vx[k] + vy[k]*vy[k] + vz[k]*vz[k];
            outp[n] = fmaxf(vv + 2.0f * best[k], 0.0f);
        }
    } else {
        // ---- dist2: each thread owns 8 p-points; min over a 256-point v chunk ----
        blk -= D1_BLOCKS;
        const int c  = blk % NSPLIT;
        const int mb = (blk / NSPLIT) % D2_MBLK;
        const int b  = blk / (NSPLIT * D2_MBLK);
        const float* pcb = pc + (size_t)b * 3 * MPTS;

        {   // stage v chunk: (vx,vy,vz, 0.5*||v||^2)
            const int n = c * NLEN + tid;
            const float sx = (vtop(vert, b, 0, n) - 0.5f) * 2.0f;
            const float sy = (vtop(vert, b, 1, n) - 0.5f) * 2.0f;
            const float sz = (vtop(vert, b, 2, n) - 0.5f) * 2.0f;
            tile[tid] = make_float4(sx, sy, sz, 0.5f * (sx*sx + sy*sy + sz*sz));
        }

        float qx[VPT], qy[VPT], qz[VPT], best[VPT];
        const int mbase = mb * (TPB * VPT) + tid;
#pragma unroll
        for (int k = 0; k < VPT; ++k) {
            const int m = mbase + k * TPB;
            qx[k] = pcb[m];
            qy[k] = pcb[MPTS + m];
            qz[k] = pcb[2 * MPTS + m];
            best[k] = BIGF;
        }
        __syncthreads();

#pragma unroll 4
        for (int j = 0; j < NLEN; ++j) {
            const float4 t = tile[j];
#pragma unroll
            for (int k = 0; k < VPT; ++k) {
                best[k] = fminf(best[k],
                    fmaf(-qx[k], t.x, fmaf(-qy[k], t.y, fmaf(-qz[k], t.z, t.w))));
            }
        }

        float* outp = part2 + (size_t)c * (BATCH * MPTS) + (size_t)b * MPTS;
#pragma unroll
        for (int k = 0; k < VPT; ++k) {
            const int m = mbase + k * TPB;
            const float qq = qx[k]*qx[k] + qy[k]*qy[k] + qz[k]*qz[k];
            outp[m] = fmaxf(qq + 2.0f * best[k], 0.0f);
        }
    }
}

// 48 blocks: 0..15 reduce dist1 (4 pts/thread), 16..47 reduce dist2.
// Last block (ticket) finalizes out[0].
__global__ void __launch_bounds__(TPB) reduce_kernel(const float* __restrict__ part1,
                                                     const float* __restrict__ part2,
                                                     const float* __restrict__ pc,
                                                     float* __restrict__ ctrl,
                                                     float* __restrict__ out) {
    const int tid = threadIdx.x;
    const int wid = tid >> 6;
    __shared__ float rs[4], rc[4];

    float s = 0.0f, cn = 0.0f;
    int b;

    if (blockIdx.x < R1_BLOCKS) {
        const int gid = blockIdx.x * (TPB * 4) + tid * 4;   // [0, BATCH*NPTS)
        b = gid / NPTS;
        float4 best = make_float4(BIGF, BIGF, BIGF, BIGF);
#pragma unroll
        for (int c = 0; c < MSPLIT; ++c) {
            const float4 v = *(const float4*)&part1[(size_t)c * (BATCH * NPTS) + gid];
            best.x = fminf(best.x, v.x); best.y = fminf(best.y, v.y);
            best.z = fminf(best.z, v.z); best.w = fminf(best.w, v.w);
        }
        s = best.x + best.y + best.z + best.w;
    } else {
        const int g2 = (blockIdx.x - R1_BLOCKS) * (TPB * 4) + tid * 4;  // [0, BATCH*MPTS)
        b = g2 / MPTS;
        const int m = g2 % MPTS;
        float4 best = make_float4(BIGF, BIGF, BIGF, BIGF);
#pragma unroll
        for (int c = 0; c < NSPLIT; ++c) {
            const float4 v = *(const float4*)&part2[(size_t)c * (BATCH * MPTS) + g2];
            best.x = fminf(best.x, v.x); best.y = fminf(best.y, v.y);
            best.z = fminf(best.z, v.z); best.w = fminf(best.w, v.w);
        }
        const float* pcb = pc + (size_t)b * 3 * MPTS;
        const float4 qx = *(const float4*)&pcb[m];
        const float4 qy = *(const float4*)&pcb[MPTS + m];
        const float4 qz = *(const float4*)&pcb[2 * MPTS + m];
        const bool v0 = !(qx.x == 0.0f && qy.x == 0.0f && qz.x == 0.0f);
        const bool v1 = !(qx.y == 0.0f && qy.y == 0.0f && qz.y == 0.0f);
        const bool v2 = !(qx.z == 0.0f && qy.z == 0.0f && qz.z == 0.0f);
        const bool v3 = !(qx.w == 0.0f && qy.w == 0.0f && qz.w == 0.0f);
        s  = (v0 ? best.x : 0.0f) + (v1 ? best.y : 0.0f)
           + (v2 ? best.z : 0.0f) + (v3 ? best.w : 0.0f);
        cn = (float)v0 + (float)v1 + (float)v2 + (float)v3;
    }

    // wave reduce (width 64), then cross-wave via LDS
    for (int off = 32; off > 0; off >>= 1) {
        s  += __shfl_down(s, off, 64);
        cn += __shfl_down(cn, off, 64);
    }
    if ((tid & 63) == 0) { rs[wid] = s; rc[wid] = cn; }
    __syncthreads();

    if (tid == 0) {
        const float ts = rs[0] + rs[1] + rs[2] + rs[3];
        if (blockIdx.x < R1_BLOCKS) {
            atomicAdd(&ctrl[b], ts);
        } else {
            atomicAdd(&ctrl[4 + b], ts);
            atomicAdd(&ctrl[8 + b], rc[0] + rc[1] + rc[2] + rc[3]);
        }
        __threadfence();
        const unsigned int old = atomicAdd((unsigned int*)&ctrl[15], 1u);
        if (old == R_BLOCKS - 1) {
            // last block: all sums are globally visible; read via atomic RMW
            float t = 0.0f;
            for (int bb = 0; bb < BATCH; ++bb) {
                const float s1 = atomicAdd(&ctrl[bb], 0.0f);
                const float s2 = atomicAdd(&ctrl[4 + bb], 0.0f);
                const float nv = atomicAdd(&ctrl[8 + bb], 0.0f);
                t += s1 * (1.0f / (float)NPTS) + s2 / fmaxf(nv, 1.0f);
            }
            out[0] = t * (1.0f / (float)BATCH);
        }
    }
}

extern "C" void kernel_launch(void* const* d_in, const int* in_sizes, int n_in,
                              void* d_out, int out_size, void* d_ws, size_t ws_size,
                              hipStream_t stream) {
    const float* vert = (const float*)d_in[0];
    const float* pc   = (const float*)d_in[1];
    float* out = (float*)d_out;

    float* part1 = (float*)d_ws;
    float* part2 = part1 + PART1_ELEMS;
    float* ctrl  = part2 + PART2_ELEMS;   // 16 floats

    dist_kernel<<<D1_BLOCKS + D2_BLOCKS, TPB, 0, stream>>>(vert, pc, part1, part2, ctrl);
    reduce_kernel<<<R_BLOCKS, TPB, 0, stream>>>(part1, part2, pc, ctrl, out);
}